// Round 2
// baseline (5178.062 us; speedup 1.0000x reference)
//
#include <hip/hip_runtime.h>
#include <stdint.h>

#define NN 100000
#define NE 1600000
#define NB 4096
#define FIN 92
#define H 51
#define H3 153
#define TSTEPS 7

// ---------------- static device workspace (zero-init BSS; no hipMalloc) ----------------
__device__ float g_x1[(size_t)NN * 52 + 64];   // lrelu(x@W1+b1), row stride 52 (pad col = 0)
__device__ float g_xr[NN];                     // x1 @ att_r
__device__ float g_en[NE];                     // exp(edge logit)
__device__ float g_sn[NN];                     // softmax denom per dst node (atomic)
__device__ float g_agg[(size_t)NN * H + 64];   // segsum(alpha * xe) per dst (atomic)
__device__ float g_x2[(size_t)NN * H + 64];    // node state after GRU1 + relu
__device__ float g_xl[(size_t)NN * H + 64];    // x2 @ Wm
__device__ float g_al[NN];                     // xl @ att_src
__device__ float g_outA[NB * H + 64];
__device__ float g_outB[NB * H + 64];
__device__ int   g_gs[NB + 2];                 // graph start offsets (batch is sorted)
__device__ float g_wg1[H * H * 8];             // GRU1 weights interleaved [k][j][8]
__device__ float g_bg1[64 * 8];
__device__ float g_wg2[H * H * 8];
__device__ float g_bg2[64 * 8];
__device__ float g_wv[64];                     // Wm @ att_dst

__device__ __forceinline__ float lrelu(float v) { return v > 0.f ? v : 0.01f * v; }
__device__ __forceinline__ float elu1(float v) { return v > 0.f ? v : expm1f(v); }
__device__ __forceinline__ float sigm(float v) { return 1.f / (1.f + __expf(-v)); }

__device__ __forceinline__ float wave_sum(float v) {
    v += __shfl_xor(v, 32, 64);
    v += __shfl_xor(v, 16, 64);
    v += __shfl_xor(v, 8, 64);
    v += __shfl_xor(v, 4, 64);
    v += __shfl_xor(v, 2, 64);
    v += __shfl_xor(v, 1, 64);
    return v;
}

// ---------------- prep ----------------
__global__ __launch_bounds__(256) void k_zero() {
    size_t i = (size_t)blockIdx.x * 256 + threadIdx.x;
    if (i < (size_t)NN * H) g_agg[i] = 0.f;
    if (i < NN) g_sn[i] = 0.f;
}

__global__ void k_pack_gru(const float* __restrict__ Wih, const float* __restrict__ bih,
                           const float* __restrict__ Whh, const float* __restrict__ bhh, int which) {
    int kj = blockIdx.x * 256 + threadIdx.x;
    if (kj >= H * H) return;
    float* Wg = which ? g_wg2 : g_wg1;
    float* bg = which ? g_bg2 : g_bg1;
    int k = kj / H, j = kj - k * H;
    float* o = Wg + (size_t)kj * 8;
    o[0] = Wih[k * H3 + j];
    o[1] = Wih[k * H3 + H + j];
    o[2] = Wih[k * H3 + 2 * H + j];
    o[3] = Whh[k * H3 + j];
    o[4] = Whh[k * H3 + H + j];
    o[5] = Whh[k * H3 + 2 * H + j];
    o[6] = 0.f; o[7] = 0.f;
    if (kj < H) {
        float* ob = bg + (size_t)kj * 8;
        ob[0] = bih[kj]; ob[1] = bih[H + kj]; ob[2] = bih[2 * H + kj];
        ob[3] = bhh[kj]; ob[4] = bhh[H + kj]; ob[5] = bhh[2 * H + kj];
        ob[6] = 0.f; ob[7] = 0.f;
    }
}

__global__ void k_wv(const float* __restrict__ Wm, const float* __restrict__ ad) {
    int k = threadIdx.x;
    if (k >= H) return;
    float a = 0.f;
    for (int j = 0; j < H; ++j) a = fmaf(Wm[k * H + j], ad[j], a);
    g_wv[k] = a;
}

__global__ void k_gstart(const int* __restrict__ batch) {
    int n = blockIdx.x * 256 + threadIdx.x;
    if (n >= NN) return;
    int bn = batch[n];
    int bp = (n == 0) ? -1 : batch[n - 1];
    for (int b = bp + 1; b <= bn; ++b) g_gs[b] = n;
    if (n == NN - 1) for (int b = bn + 1; b <= NB; ++b) g_gs[b] = NN;
}

// ---------------- lin1: x1 = lrelu(x@W1+b1), xr = x1@att_r ----------------
__global__ __launch_bounds__(256) void k_lin1(const float* __restrict__ x, const float* __restrict__ W1,
                                              const float* __restrict__ b1, const float* __restrict__ attr_) {
    int n = blockIdx.x * 256 + threadIdx.x;
    if (n >= NN) return;
    const float4* xq4 = (const float4*)(x + (size_t)n * FIN);  // 92 floats = 23 float4, 16B aligned
    float acc[H];
#pragma unroll
    for (int h = 0; h < H; ++h) acc[h] = 0.f;
#pragma unroll 1
    for (int q = 0; q < FIN / 4; ++q) {
        float4 v = xq4[q];
        const float* wr = W1 + (4 * q) * H;
#pragma unroll
        for (int h = 0; h < H; ++h)
            acc[h] = fmaf(v.x, wr[h], fmaf(v.y, wr[H + h], fmaf(v.z, wr[2 * H + h], fmaf(v.w, wr[3 * H + h], acc[h]))));
    }
    float xrv = 0.f;
    float* xo = g_x1 + (size_t)n * 52;
#pragma unroll
    for (int h = 0; h < H; ++h) {
        float v = lrelu(acc[h] + b1[h]);
        xo[h] = v;
        xrv = fmaf(v, attr_[h], xrv);
    }
    xo[H] = 0.f;
    g_xr[n] = xrv;
}

// ---------------- shared edge transform: acc = [x1[src]|ea[e]] @ We1 (pre-lrelu) ----------------
__device__ __forceinline__ void edge_xe(const float* __restrict__ We1, int s,
                                        const float* __restrict__ ea_row, float acc[H]) {
    const float4* xq4 = (const float4*)(g_x1 + (size_t)s * 52);
#pragma unroll 1
    for (int q = 0; q < 13; ++q) {            // rows 0..51 (row 51 hits the zero pad)
        float4 xq = xq4[q];
        const float* wr = We1 + 4 * q * H;
#pragma unroll
        for (int h = 0; h < H; ++h)
            acc[h] = fmaf(xq.x, wr[h], fmaf(xq.y, wr[H + h], fmaf(xq.z, wr[2 * H + h], fmaf(xq.w, wr[3 * H + h], acc[h]))));
    }
    const float2* ea2 = (const float2*)ea_row; // 10 floats = 5 float2, 8B aligned
#pragma unroll 1
    for (int p = 0; p < 5; ++p) {
        float2 v = ea2[p];
        const float* wr = We1 + (H + 2 * p) * H;
#pragma unroll
        for (int h = 0; h < H; ++h)
            acc[h] = fmaf(v.x, wr[h], fmaf(v.y, wr[H + h], acc[h]));
    }
}

__global__ __launch_bounds__(256) void k_edge1(const int* __restrict__ ei, const float* __restrict__ ea,
                                               const float* __restrict__ We1, const float* __restrict__ attl) {
    int e = blockIdx.x * 256 + threadIdx.x;
    if (e >= NE) return;
    int s = ei[e], d = ei[NE + e];
    float acc[H];
#pragma unroll
    for (int h = 0; h < H; ++h) acc[h] = 0.f;
    edge_xe(We1, s, ea + (size_t)e * 10, acc);
    float a = 0.f;
#pragma unroll
    for (int h = 0; h < H; ++h) a = fmaf(lrelu(acc[h]), attl[h], a);
    a = lrelu(a + g_xr[d]);
    float ev = __expf(a);   // no max-subtraction: logits are O(1), ratio identical
    g_en[e] = ev;
    atomicAdd(g_sn + d, ev);
}

__global__ __launch_bounds__(256) void k_edge2(const int* __restrict__ ei, const float* __restrict__ ea,
                                               const float* __restrict__ We1) {
    int e = blockIdx.x * 256 + threadIdx.x;
    if (e >= NE) return;
    int s = ei[e], d = ei[NE + e];
    float acc[H];
#pragma unroll
    for (int h = 0; h < H; ++h) acc[h] = 0.f;
    edge_xe(We1, s, ea + (size_t)e * 10, acc);
    float alpha = g_en[e] / (g_sn[d] + 1e-16f);
    float* ag = g_agg + (size_t)d * H;
#pragma unroll
    for (int h = 0; h < H; ++h) atomicAdd(ag + h, alpha * lrelu(acc[h]));
}

// ---------------- gate(We2) + GRU1 fused: wave per node ----------------
__global__ __launch_bounds__(256) void k_gategru(const float* __restrict__ We2, const float* __restrict__ gb) {
    int lane = threadIdx.x & 63;
    int lj = lane < H ? lane : H - 1;
    int n0 = blockIdx.x * 4 + (threadIdx.x >> 6);
    if (n0 >= NN) return;
    int n = __builtin_amdgcn_readfirstlane(n0);
    const float* aggr = g_agg + (size_t)n * H;
    const float* x1r = g_x1 + (size_t)n * 52;
    float acc = 0.f;
    for (int k = 0; k < H; ++k) acc = fmaf(aggr[k], We2[k * H + lj], acc);
    float hb = elu1(acc + gb[lj]);
    float gir = 0, giz = 0, gin = 0, ghr = 0, ghz = 0, ghn = 0;
    for (int k = 0; k < H; ++k) {
        float hbk = __shfl(hb, k, 64);
        float xk = x1r[k];
        const float4* wp = (const float4*)(g_wg1 + ((size_t)(k * H + lj)) * 8);
        float4 w0 = wp[0];
        float4 w1 = wp[1];
        gir = fmaf(hbk, w0.x, gir); giz = fmaf(hbk, w0.y, giz); gin = fmaf(hbk, w0.z, gin);
        ghr = fmaf(xk, w0.w, ghr);  ghz = fmaf(xk, w1.x, ghz);  ghn = fmaf(xk, w1.y, ghn);
    }
    const float4* bp = (const float4*)(g_bg1 + lane * 8);
    float4 b0 = bp[0];
    float4 b1v = bp[1];
    float r = sigm(gir + b0.x + ghr + b0.w);
    float z = sigm(giz + b0.y + ghz + b1v.x);
    float nn2 = tanhf(gin + b0.z + r * (ghn + b1v.y));
    float xj = x1r[lane];
    float o = (1.f - z) * nn2 + z * xj;
    if (lane < H) g_x2[(size_t)n * H + lane] = fmaxf(o, 0.f);
}

// ---------------- readout: out0 = relu(segment_sum(x2, batch)) ----------------
__global__ __launch_bounds__(256) void k_readout() {
    int lane = threadIdx.x & 63;
    int b = __builtin_amdgcn_readfirstlane(blockIdx.x * 4 + (threadIdx.x >> 6));
    int gs = g_gs[b], ge = g_gs[b + 1];
    float acc = 0.f;
    for (int i = gs; i < ge; ++i) acc += g_x2[(size_t)i * H + lane];
    if (lane < H) g_outA[b * H + lane] = fmaxf(acc, 0.f);
}

// ---------------- xl = x2@Wm, al = xl@att_src ----------------
__global__ __launch_bounds__(256) void k_xl(const float* __restrict__ Wm, const float* __restrict__ asrc) {
    int lane = threadIdx.x & 63;
    int lj = lane < H ? lane : H - 1;
    int n0 = blockIdx.x * 4 + (threadIdx.x >> 6);
    if (n0 >= NN) return;
    int n = __builtin_amdgcn_readfirstlane(n0);
    const float* x2r = g_x2 + (size_t)n * H;
    float acc = 0.f;
    for (int k = 0; k < H; ++k) acc = fmaf(x2r[k], Wm[k * H + lj], acc);
    if (lane < H) g_xl[(size_t)n * H + lane] = acc;
    float v = (lane < H) ? acc * asrc[lj] : 0.f;
    v = wave_sum(v);
    if (lane == 0) g_al[n] = v;
}

// ---------------- one molecular-attention timestep, fused, wave per graph ----------------
__global__ __launch_bounds__(256) void k_mol(int dir, const float* __restrict__ mb,
                                             const float* __restrict__ W2, const float* __restrict__ b2,
                                             int last, float* __restrict__ dout) {
    int lane = threadIdx.x & 63;
    int lj = lane < H ? lane : H - 1;
    int b = __builtin_amdgcn_readfirstlane(blockIdx.x * 4 + (threadIdx.x >> 6));
    const float* orow = (dir ? g_outB : g_outA) + (size_t)b * H;
    float* oOut = (dir ? g_outA : g_outB) + (size_t)b * H;
    float oj = orow[lane];
    float v = (lane < H) ? oj * g_wv[lane] : 0.f;
    float arb = wave_sum(v);
    int gs = g_gs[b], ge = g_gs[b + 1];
    // softmax denom over this graph's nodes
    float ssum = 0.f;
    for (int base = gs; base < ge; base += 64) {
        int i = base + lane;
        float ev = (i < ge) ? __expf(lrelu(g_al[i] + arb)) : 0.f;
        ssum += ev;
    }
    ssum = wave_sum(ssum);
    float inv = 1.f / (ssum + 1e-16f);
    // weighted sum of xl rows (lane = channel)
    float acc = 0.f;
    for (int i = gs; i < ge; ++i) {
        float evi = __expf(lrelu(g_al[i] + arb));
        acc = fmaf(evi * inv, g_xl[(size_t)i * H + lane], acc);
    }
    float hm = elu1(acc + mb[lj]);
    // GRU2
    float gir = 0, giz = 0, gin = 0, ghr = 0, ghz = 0, ghn = 0;
    for (int k = 0; k < H; ++k) {
        float hmk = __shfl(hm, k, 64);
        float ok = orow[k];
        const float4* wp = (const float4*)(g_wg2 + ((size_t)(k * H + lj)) * 8);
        float4 w0 = wp[0];
        float4 w1 = wp[1];
        gir = fmaf(hmk, w0.x, gir); giz = fmaf(hmk, w0.y, giz); gin = fmaf(hmk, w0.z, gin);
        ghr = fmaf(ok, w0.w, ghr);  ghz = fmaf(ok, w1.x, ghz);  ghn = fmaf(ok, w1.y, ghn);
    }
    const float4* bp = (const float4*)(g_bg2 + lane * 8);
    float4 b0 = bp[0];
    float4 b1v = bp[1];
    float r = sigm(gir + b0.x + ghr + b0.w);
    float z = sigm(giz + b0.y + ghz + b1v.x);
    float nn2 = tanhf(gin + b0.z + r * (ghn + b1v.y));
    float o = (1.f - z) * nn2 + z * oj;
    float newo = fmaxf(o, 0.f);
    if (lane < H) oOut[lane] = newo;
    if (last) {
        float fv = (lane < H) ? newo * W2[lj] : 0.f;
        fv = wave_sum(fv);
        if (lane == 0) dout[b] = fv + b2[0];
    }
}

extern "C" void kernel_launch(void* const* d_in, const int* in_sizes, int n_in,
                              void* d_out, int out_size, void* d_ws, size_t ws_size,
                              hipStream_t stream) {
    const float* x     = (const float*)d_in[0];
    const int*   ei    = (const int*)d_in[1];
    const float* ea    = (const float*)d_in[2];
    const int*   batch = (const int*)d_in[3];
    const float* W1    = (const float*)d_in[4];
    const float* b1    = (const float*)d_in[5];
    const float* We1   = (const float*)d_in[6];
    const float* attl  = (const float*)d_in[7];
    const float* attr_ = (const float*)d_in[8];
    const float* We2   = (const float*)d_in[9];
    const float* gb    = (const float*)d_in[10];
    const float* Wm    = (const float*)d_in[15];
    const float* asrc  = (const float*)d_in[16];
    const float* adst  = (const float*)d_in[17];
    const float* mb    = (const float*)d_in[18];
    const float* W2    = (const float*)d_in[23];
    const float* b2    = (const float*)d_in[24];
    float* dout = (float*)d_out;

    k_zero<<<(NN * H + 255) / 256, 256, 0, stream>>>();
    k_pack_gru<<<(H * H + 255) / 256, 256, 0, stream>>>((const float*)d_in[11], (const float*)d_in[12],
                                                        (const float*)d_in[13], (const float*)d_in[14], 0);
    k_pack_gru<<<(H * H + 255) / 256, 256, 0, stream>>>((const float*)d_in[19], (const float*)d_in[20],
                                                        (const float*)d_in[21], (const float*)d_in[22], 1);
    k_wv<<<1, 64, 0, stream>>>(Wm, adst);
    k_gstart<<<(NN + 255) / 256, 256, 0, stream>>>(batch);

    k_lin1<<<(NN + 255) / 256, 256, 0, stream>>>(x, W1, b1, attr_);
    k_edge1<<<NE / 256, 256, 0, stream>>>(ei, ea, We1, attl);
    k_edge2<<<NE / 256, 256, 0, stream>>>(ei, ea, We1);
    k_gategru<<<NN / 4, 256, 0, stream>>>(We2, gb);
    k_readout<<<NB / 4, 256, 0, stream>>>();
    k_xl<<<NN / 4, 256, 0, stream>>>(Wm, asrc);

    for (int t = 0; t < TSTEPS; ++t) {
        k_mol<<<NB / 4, 256, 0, stream>>>(t & 1, mb, W2, b2, (t == TSTEPS - 1) ? 1 : 0, dout);
    }
}

// Round 3
// 1408.622 us; speedup vs baseline: 3.6760x; 3.6760x over previous
//
#include <hip/hip_runtime.h>
#include <stdint.h>

#define NN 100000
#define NE 1600000
#define NB 4096
#define FIN 92
#define H 51
#define H3 153
#define TSTEPS 7
#define SCAN_B 391   // ceil(NN/256)

// ---------------- static device workspace (BSS; no hipMalloc) ----------------
__device__ float g_x1[(size_t)NN * 52 + 64];   // lrelu(x@W1+b1), row stride 52 (pad col = 0)
__device__ float g_xr[NN];                     // x1 @ att_r
__device__ float g_agg[(size_t)NN * H + 64];   // segsum(alpha * lrelu(xe)) per dst (normalized)
__device__ float g_x2[(size_t)NN * H + 64];    // node state after GRU1 + relu
__device__ float g_xl[(size_t)NN * H + 64];    // x2 @ Wm
__device__ float g_al[NN];                     // xl @ att_src
__device__ float g_outA[NB * H + 64];
__device__ float g_outB[NB * H + 64];
__device__ int   g_gs[NB + 2];                 // graph start offsets (batch is sorted)
__device__ float g_wg1[H * H * 8];             // GRU1 weights interleaved [k][j][8]
__device__ float g_bg1[64 * 8];
__device__ float g_wg2[H * H * 8];
__device__ float g_bg2[64 * 8];
__device__ float g_wv[64];                     // Wm @ att_dst
// CSR scratch
__device__ int g_cnt[NN];                      // per-dst degree histogram
__device__ int g_rp[NN + 1];                   // rowptr (exclusive)
__device__ int g_cur[NN];                      // fill cursor
__device__ int g_eid[NE];                      // edge ids grouped by dst
__device__ int g_bsum[512];
__device__ int g_boff[512];

__device__ __forceinline__ float lrelu(float v) { return v > 0.f ? v : 0.01f * v; }
__device__ __forceinline__ float elu1(float v) { return v > 0.f ? v : expm1f(v); }
__device__ __forceinline__ float sigm(float v) { return 1.f / (1.f + __expf(-v)); }

__device__ __forceinline__ float wave_sum(float v) {
    v += __shfl_xor(v, 32, 64);
    v += __shfl_xor(v, 16, 64);
    v += __shfl_xor(v, 8, 64);
    v += __shfl_xor(v, 4, 64);
    v += __shfl_xor(v, 2, 64);
    v += __shfl_xor(v, 1, 64);
    return v;
}

// ---------------- prep ----------------
__global__ __launch_bounds__(256) void k_zero() {
    int i = blockIdx.x * 256 + threadIdx.x;
    if (i < NN) g_cnt[i] = 0;
}

__global__ void k_pack_gru(const float* __restrict__ Wih, const float* __restrict__ bih,
                           const float* __restrict__ Whh, const float* __restrict__ bhh, int which) {
    int kj = blockIdx.x * 256 + threadIdx.x;
    if (kj >= H * H) return;
    float* Wg = which ? g_wg2 : g_wg1;
    float* bg = which ? g_bg2 : g_bg1;
    int k = kj / H, j = kj - k * H;
    float* o = Wg + (size_t)kj * 8;
    o[0] = Wih[k * H3 + j];
    o[1] = Wih[k * H3 + H + j];
    o[2] = Wih[k * H3 + 2 * H + j];
    o[3] = Whh[k * H3 + j];
    o[4] = Whh[k * H3 + H + j];
    o[5] = Whh[k * H3 + 2 * H + j];
    o[6] = 0.f; o[7] = 0.f;
    if (kj < H) {
        float* ob = bg + (size_t)kj * 8;
        ob[0] = bih[kj]; ob[1] = bih[H + kj]; ob[2] = bih[2 * H + kj];
        ob[3] = bhh[kj]; ob[4] = bhh[H + kj]; ob[5] = bhh[2 * H + kj];
        ob[6] = 0.f; ob[7] = 0.f;
    }
}

__global__ void k_wv(const float* __restrict__ Wm, const float* __restrict__ ad) {
    int k = threadIdx.x;
    if (k >= H) return;
    float a = 0.f;
    for (int j = 0; j < H; ++j) a = fmaf(Wm[k * H + j], ad[j], a);
    g_wv[k] = a;
}

__global__ void k_gstart(const int* __restrict__ batch) {
    int n = blockIdx.x * 256 + threadIdx.x;
    if (n >= NN) return;
    int bn = batch[n];
    int bp = (n == 0) ? -1 : batch[n - 1];
    for (int b = bp + 1; b <= bn; ++b) g_gs[b] = n;
    if (n == NN - 1) for (int b = bn + 1; b <= NB; ++b) g_gs[b] = NN;
}

// ---------------- CSR build ----------------
__global__ __launch_bounds__(256) void k_count(const int* __restrict__ ei) {
    int e = blockIdx.x * 256 + threadIdx.x;
    if (e >= NE) return;
    atomicAdd(&g_cnt[ei[NE + e]], 1);
}

__global__ __launch_bounds__(256) void k_scan1() {
    __shared__ int sm[256];
    int tid = threadIdx.x;
    int i = blockIdx.x * 256 + tid;
    sm[tid] = (i < NN) ? g_cnt[i] : 0;
    __syncthreads();
#pragma unroll
    for (int off = 1; off < 256; off <<= 1) {
        int t = (tid >= off) ? sm[tid - off] : 0;
        __syncthreads();
        sm[tid] += t;
        __syncthreads();
    }
    if (i < NN) g_rp[i + 1] = sm[tid];     // block-local inclusive
    if (tid == 255) g_bsum[blockIdx.x] = sm[255];
}

__global__ void k_scan2() {
    __shared__ int sm[512];
    int tid = threadIdx.x;  // 512 threads
    sm[tid] = (tid < SCAN_B) ? g_bsum[tid] : 0;
    __syncthreads();
#pragma unroll
    for (int off = 1; off < 512; off <<= 1) {
        int t = (tid >= off) ? sm[tid - off] : 0;
        __syncthreads();
        sm[tid] += t;
        __syncthreads();
    }
    if (tid < SCAN_B) g_boff[tid] = (tid == 0) ? 0 : sm[tid - 1];
}

__global__ __launch_bounds__(256) void k_scan3() {
    int i = blockIdx.x * 256 + threadIdx.x;
    if (i >= NN) return;
    int v = g_rp[i + 1] + g_boff[blockIdx.x];   // final inclusive scan value at i
    g_rp[i + 1] = v;
    if (i == 0) { g_rp[0] = 0; g_cur[0] = 0; }
    if (i + 1 < NN) g_cur[i + 1] = v;
}

__global__ __launch_bounds__(256) void k_fill(const int* __restrict__ ei) {
    int e = blockIdx.x * 256 + threadIdx.x;
    if (e >= NE) return;
    int d = ei[NE + e];
    int pos = atomicAdd(&g_cur[d], 1);
    g_eid[pos] = e;
}

// ---------------- lin1: x1 = lrelu(x@W1+b1), xr = x1@att_r ----------------
__global__ __launch_bounds__(256) void k_lin1(const float* __restrict__ x, const float* __restrict__ W1,
                                              const float* __restrict__ b1, const float* __restrict__ attr_) {
    int n = blockIdx.x * 256 + threadIdx.x;
    if (n >= NN) return;
    const float4* xq4 = (const float4*)(x + (size_t)n * FIN);  // 92 floats = 23 float4
    float acc[H];
#pragma unroll
    for (int h = 0; h < H; ++h) acc[h] = 0.f;
#pragma unroll 1
    for (int q = 0; q < FIN / 4; ++q) {
        float4 v = xq4[q];
        const float* wr = W1 + (4 * q) * H;
#pragma unroll
        for (int h = 0; h < H; ++h)
            acc[h] = fmaf(v.x, wr[h], fmaf(v.y, wr[H + h], fmaf(v.z, wr[2 * H + h], fmaf(v.w, wr[3 * H + h], acc[h]))));
    }
    float xrv = 0.f;
    float* xo = g_x1 + (size_t)n * 52;
#pragma unroll
    for (int h = 0; h < H; ++h) {
        float v = lrelu(acc[h] + b1[h]);
        xo[h] = v;
        xrv = fmaf(v, attr_[h], xrv);
    }
    xo[H] = 0.f;
    g_xr[n] = xrv;
}

// ---------------- GATEConv, single pass: wave per dst node, lane = channel ----------------
// agg[d] = sum_e exp(a_e) * lrelu(xe_e) / (sum_e exp(a_e) + 1e-16)
__global__ __launch_bounds__(256) void k_gate(const int* __restrict__ ei, const float* __restrict__ ea,
                                              const float* __restrict__ We1, const float* __restrict__ attl) {
    int lane = threadIdx.x & 63;
    int lj = lane < H ? lane : H - 1;
    int n0 = blockIdx.x * 4 + (threadIdx.x >> 6);
    if (n0 >= NN) return;
    int n = __builtin_amdgcn_readfirstlane(n0);
    // We1 column for this lane's output channel; index 51 multiplies the x1 pad -> 0
    float wcol[62];
#pragma unroll
    for (int k = 0; k < H; ++k) wcol[k] = We1[k * H + lj];
    wcol[51] = 0.f;
#pragma unroll
    for (int p = 0; p < 10; ++p) wcol[52 + p] = We1[(H + p) * H + lj];
    float attlv = attl[lj];
    float xrd = g_xr[n];
    int rs = g_rp[n], re = g_rp[n + 1];
    float accH = 0.f, den = 0.f;
    for (int idx = rs; idx < re; ++idx) {
        int e = g_eid[idx];          // wave-uniform
        int s = ei[e];               // wave-uniform
        const float4* xq = (const float4*)(g_x1 + (size_t)s * 52);
        float xe = 0.f;
#pragma unroll
        for (int q = 0; q < 13; ++q) {
            float4 v = xq[q];
            xe = fmaf(v.x, wcol[4 * q], fmaf(v.y, wcol[4 * q + 1],
                 fmaf(v.z, wcol[4 * q + 2], fmaf(v.w, wcol[4 * q + 3], xe))));
        }
        const float2* e2 = (const float2*)(ea + (size_t)e * 10);
#pragma unroll
        for (int p = 0; p < 5; ++p) {
            float2 v = e2[p];
            xe = fmaf(v.x, wcol[52 + 2 * p], fmaf(v.y, wcol[53 + 2 * p], xe));
        }
        float xel = lrelu(xe);
        float a = wave_sum((lane < H) ? xel * attlv : 0.f);
        a = lrelu(a + xrd);
        float en = __expf(a);        // no max-subtraction: logits O(1), ratio identical
        accH = fmaf(en, xel, accH);
        den += en;
    }
    if (lane < H) g_agg[(size_t)n * H + lane] = accH / (den + 1e-16f);
}

// ---------------- gate(We2) + GRU1 fused: wave per node ----------------
__global__ __launch_bounds__(256) void k_gategru(const float* __restrict__ We2, const float* __restrict__ gb) {
    int lane = threadIdx.x & 63;
    int lj = lane < H ? lane : H - 1;
    int n0 = blockIdx.x * 4 + (threadIdx.x >> 6);
    if (n0 >= NN) return;
    int n = __builtin_amdgcn_readfirstlane(n0);
    const float* aggr = g_agg + (size_t)n * H;
    const float* x1r = g_x1 + (size_t)n * 52;
    float acc = 0.f;
    for (int k = 0; k < H; ++k) acc = fmaf(aggr[k], We2[k * H + lj], acc);
    float hb = elu1(acc + gb[lj]);
    float gir = 0, giz = 0, gin = 0, ghr = 0, ghz = 0, ghn = 0;
    for (int k = 0; k < H; ++k) {
        float hbk = __shfl(hb, k, 64);
        float xk = x1r[k];
        const float4* wp = (const float4*)(g_wg1 + ((size_t)(k * H + lj)) * 8);
        float4 w0 = wp[0];
        float4 w1 = wp[1];
        gir = fmaf(hbk, w0.x, gir); giz = fmaf(hbk, w0.y, giz); gin = fmaf(hbk, w0.z, gin);
        ghr = fmaf(xk, w0.w, ghr);  ghz = fmaf(xk, w1.x, ghz);  ghn = fmaf(xk, w1.y, ghn);
    }
    const float4* bp = (const float4*)(g_bg1 + lane * 8);
    float4 b0 = bp[0];
    float4 b1v = bp[1];
    float r = sigm(gir + b0.x + ghr + b0.w);
    float z = sigm(giz + b0.y + ghz + b1v.x);
    float nn2 = tanhf(gin + b0.z + r * (ghn + b1v.y));
    float xj = x1r[lane];
    float o = (1.f - z) * nn2 + z * xj;
    if (lane < H) g_x2[(size_t)n * H + lane] = fmaxf(o, 0.f);
}

// ---------------- readout: out0 = relu(segment_sum(x2, batch)) ----------------
__global__ __launch_bounds__(256) void k_readout() {
    int lane = threadIdx.x & 63;
    int b = __builtin_amdgcn_readfirstlane(blockIdx.x * 4 + (threadIdx.x >> 6));
    int gs = g_gs[b], ge = g_gs[b + 1];
    float acc = 0.f;
    for (int i = gs; i < ge; ++i) acc += g_x2[(size_t)i * H + lane];
    if (lane < H) g_outA[b * H + lane] = fmaxf(acc, 0.f);
}

// ---------------- xl = x2@Wm, al = xl@att_src ----------------
__global__ __launch_bounds__(256) void k_xl(const float* __restrict__ Wm, const float* __restrict__ asrc) {
    int lane = threadIdx.x & 63;
    int lj = lane < H ? lane : H - 1;
    int n0 = blockIdx.x * 4 + (threadIdx.x >> 6);
    if (n0 >= NN) return;
    int n = __builtin_amdgcn_readfirstlane(n0);
    const float* x2r = g_x2 + (size_t)n * H;
    float acc = 0.f;
    for (int k = 0; k < H; ++k) acc = fmaf(x2r[k], Wm[k * H + lj], acc);
    if (lane < H) g_xl[(size_t)n * H + lane] = acc;
    float v = (lane < H) ? acc * asrc[lj] : 0.f;
    v = wave_sum(v);
    if (lane == 0) g_al[n] = v;
}

// ---------------- one molecular-attention timestep, fused, wave per graph ----------------
__global__ __launch_bounds__(256) void k_mol(int dir, const float* __restrict__ mb,
                                             const float* __restrict__ W2, const float* __restrict__ b2,
                                             int last, float* __restrict__ dout) {
    int lane = threadIdx.x & 63;
    int lj = lane < H ? lane : H - 1;
    int b = __builtin_amdgcn_readfirstlane(blockIdx.x * 4 + (threadIdx.x >> 6));
    const float* orow = (dir ? g_outB : g_outA) + (size_t)b * H;
    float* oOut = (dir ? g_outA : g_outB) + (size_t)b * H;
    float oj = orow[lane];
    float v = (lane < H) ? oj * g_wv[lane] : 0.f;
    float arb = wave_sum(v);
    int gs = g_gs[b], ge = g_gs[b + 1];
    float ssum = 0.f;
    for (int base = gs; base < ge; base += 64) {
        int i = base + lane;
        float ev = (i < ge) ? __expf(lrelu(g_al[i] + arb)) : 0.f;
        ssum += ev;
    }
    ssum = wave_sum(ssum);
    float inv = 1.f / (ssum + 1e-16f);
    float acc = 0.f;
    for (int i = gs; i < ge; ++i) {
        float evi = __expf(lrelu(g_al[i] + arb));
        acc = fmaf(evi * inv, g_xl[(size_t)i * H + lane], acc);
    }
    float hm = elu1(acc + mb[lj]);
    float gir = 0, giz = 0, gin = 0, ghr = 0, ghz = 0, ghn = 0;
    for (int k = 0; k < H; ++k) {
        float hmk = __shfl(hm, k, 64);
        float ok = orow[k];
        const float4* wp = (const float4*)(g_wg2 + ((size_t)(k * H + lj)) * 8);
        float4 w0 = wp[0];
        float4 w1 = wp[1];
        gir = fmaf(hmk, w0.x, gir); giz = fmaf(hmk, w0.y, giz); gin = fmaf(hmk, w0.z, gin);
        ghr = fmaf(ok, w0.w, ghr);  ghz = fmaf(ok, w1.x, ghz);  ghn = fmaf(ok, w1.y, ghn);
    }
    const float4* bp = (const float4*)(g_bg2 + lane * 8);
    float4 b0 = bp[0];
    float4 b1v = bp[1];
    float r = sigm(gir + b0.x + ghr + b0.w);
    float z = sigm(giz + b0.y + ghz + b1v.x);
    float nn2 = tanhf(gin + b0.z + r * (ghn + b1v.y));
    float o = (1.f - z) * nn2 + z * oj;
    float newo = fmaxf(o, 0.f);
    if (lane < H) oOut[lane] = newo;
    if (last) {
        float fv = (lane < H) ? newo * W2[lj] : 0.f;
        fv = wave_sum(fv);
        if (lane == 0) dout[b] = fv + b2[0];
    }
}

extern "C" void kernel_launch(void* const* d_in, const int* in_sizes, int n_in,
                              void* d_out, int out_size, void* d_ws, size_t ws_size,
                              hipStream_t stream) {
    const float* x     = (const float*)d_in[0];
    const int*   ei    = (const int*)d_in[1];
    const float* ea    = (const float*)d_in[2];
    const int*   batch = (const int*)d_in[3];
    const float* W1    = (const float*)d_in[4];
    const float* b1    = (const float*)d_in[5];
    const float* We1   = (const float*)d_in[6];
    const float* attl  = (const float*)d_in[7];
    const float* attr_ = (const float*)d_in[8];
    const float* We2   = (const float*)d_in[9];
    const float* gb    = (const float*)d_in[10];
    const float* Wm    = (const float*)d_in[15];
    const float* asrc  = (const float*)d_in[16];
    const float* adst  = (const float*)d_in[17];
    const float* mb    = (const float*)d_in[18];
    const float* W2    = (const float*)d_in[23];
    const float* b2    = (const float*)d_in[24];
    float* dout = (float*)d_out;

    // CSR build
    k_zero<<<SCAN_B, 256, 0, stream>>>();
    k_count<<<NE / 256, 256, 0, stream>>>(ei);
    k_scan1<<<SCAN_B, 256, 0, stream>>>();
    k_scan2<<<1, 512, 0, stream>>>();
    k_scan3<<<SCAN_B, 256, 0, stream>>>();
    k_fill<<<NE / 256, 256, 0, stream>>>(ei);

    // weight prep
    k_pack_gru<<<(H * H + 255) / 256, 256, 0, stream>>>((const float*)d_in[11], (const float*)d_in[12],
                                                        (const float*)d_in[13], (const float*)d_in[14], 0);
    k_pack_gru<<<(H * H + 255) / 256, 256, 0, stream>>>((const float*)d_in[19], (const float*)d_in[20],
                                                        (const float*)d_in[21], (const float*)d_in[22], 1);
    k_wv<<<1, 64, 0, stream>>>(Wm, adst);
    k_gstart<<<(NN + 255) / 256, 256, 0, stream>>>(batch);

    // main pipeline
    k_lin1<<<(NN + 255) / 256, 256, 0, stream>>>(x, W1, b1, attr_);
    k_gate<<<NN / 4, 256, 0, stream>>>(ei, ea, We1, attl);
    k_gategru<<<NN / 4, 256, 0, stream>>>(We2, gb);
    k_readout<<<NB / 4, 256, 0, stream>>>();
    k_xl<<<NN / 4, 256, 0, stream>>>(Wm, asrc);

    for (int t = 0; t < TSTEPS; ++t) {
        k_mol<<<NB / 4, 256, 0, stream>>>(t & 1, mb, W2, b2, (t == TSTEPS - 1) ? 1 : 0, dout);
    }
}